// Round 21
// baseline (391.706 us; speedup 1.0000x reference)
//
#include <hip/hip_runtime.h>

#define NN 40000
#define EE 640000
#define MAXT 58752   // >= (EE + 31*NN)/32, exact worst-case padded-tile bound
#define SCAN_B 157   // ceil(NN/256)

typedef unsigned short u16;
typedef unsigned int u32;
typedef unsigned long long u64;
typedef __attribute__((ext_vector_type(8))) short short8;
typedef __attribute__((ext_vector_type(4))) float f32x4;
typedef __attribute__((ext_vector_type(16))) float f32x16;

__device__ __forceinline__ float bf2f(u16 b){ u32 u=((u32)b)<<16; float f; __builtin_memcpy(&f,&u,4); return f; }
__device__ __forceinline__ u16 f2bf(float f){ u32 u; __builtin_memcpy(&u,&f,4); u = (u + 0x7fffu + ((u>>16)&1u))>>16; return (u16)u; }

// P-layout: 128-wide node buffers store column c at position
// pos(c) = ((c&15)<<3)|(c>>4); orig(p) = ((p&7)<<4)|(p>>3).
__device__ __forceinline__ int origcol(int p){ return ((p & 7) << 4) | (p >> 3); }

#define MFMA __builtin_amdgcn_mfma_f32_16x16x32_bf16
#define MFMA32 __builtin_amdgcn_mfma_f32_32x32x16_bf16

// ---- pack ALL 8 weight matrices (f32) -> bf16 B-fragment order, one launch ----
__global__ __launch_bounds__(256)
void packall_kernel(const float* __restrict__ mw1, const float* __restrict__ mw2,
                    const float* __restrict__ uw1, const float* __restrict__ uw2,
                    u16* __restrict__ dm1, u16* __restrict__ dm2,
                    u16* __restrict__ du1, u16* __restrict__ du2){
    int idx = blockIdx.x*blockDim.x + threadIdx.x;   // 4 * 65536
    if (idx >= 4*65536) return;
    int a = idx >> 16, rem = idx & 65535;
    int l = rem >> 15, e = rem & 32767;
    const float* src; u16* dst;
    if (a == 0){ src = mw1; dst = dm1; }
    else if (a == 1){ src = uw1; dst = du1; }
    else if (a == 2){ src = mw2; dst = dm2; }
    else { src = uw2; dst = du2; }
    float v; int o;
    if (a < 2){
        int k = e >> 8, n = e & 255;          // k = NEW k (P-layout position)
        v = src[l*32768 + origcol(k)*256 + n];
        o = (((k>>5)*16 + (n>>4))*64 + ((k>>3)&3)*16 + (n&15))*8 + (k&7);
    } else {
        int k = e >> 7, n = e & 127;
        v = src[l*32768 + e];
        o = (((k>>5)*8 + (n>>4))*64 + ((k>>3)&3)*16 + (n&15))*8 + (k&7);
    }
    dst[l*32768 + o] = f2bf(v);
}

// ================== node-side fused MLP (modes 0/1) ==================
// LDS: w1f 64KB @0, w2f 64KB @65536, stg 20KB @131072 -> 151552
#define SMEM_BYTES 151552

template<int MODE>
__global__ __launch_bounds__(512, 1)
void mlp_kernel(const u16* __restrict__ xa, const u16* __restrict__ xb,
                const u16* __restrict__ w1fg, const float* __restrict__ b1g,
                const u16* __restrict__ w2fg, const float* __restrict__ b2g,
                u16* __restrict__ out16, u16* __restrict__ hmaxb, int ntiles)
{
    extern __shared__ char smem[];
    short8* w1f = (short8*)smem;
    short8* w2f = (short8*)(smem + 65536);
    u16* stg_all = (u16*)(smem + 131072);

    const int tid = threadIdx.x;
    {   // fast prologue: 128KB linear copy from pre-packed fragments
        const short8* s1 = (const short8*)w1fg;
        const short8* s2 = (const short8*)w2fg;
        #pragma unroll
        for (int i = 0; i < 8; ++i) w1f[tid + i*512] = s1[tid + i*512];
        #pragma unroll
        for (int i = 0; i < 8; ++i) w2f[tid + i*512] = s2[tid + i*512];
    }
    __syncthreads();

    const int wave = tid >> 6, lane = tid & 63;
    const int g = lane >> 4, c16 = lane & 15;
    u16* stg = stg_all + wave*1280;   // 32 rows * 40 u16

    const int wid0 = blockIdx.x*8 + wave;
    const int nwaves = gridDim.x*8;

    for (int t = wid0; t < ntiles; t += nwaves) {
        short8 a[2][4];
        if (MODE == 0) {
            #pragma unroll
            for (int sub = 0; sub < 2; ++sub){
                int r = t*32 + sub*16 + c16;
                #pragma unroll
                for (int kt = 0; kt < 4; ++kt)
                    a[sub][kt] = *(const short8*)(xa + r*128 + kt*32 + g*8);
            }
        } else {
            int r = t*16 + c16;
            #pragma unroll
            for (int kt = 0; kt < 4; ++kt){
                a[0][kt] = *(const short8*)(xa + r*128 + kt*32 + g*8);
                a[1][kt] = *(const short8*)(xb + r*128 + kt*32 + g*8);
            }
        }

        f32x4 oacc[2][8];
        #pragma unroll
        for (int s = 0; s < 2; ++s)
            #pragma unroll
            for (int o = 0; o < 8; ++o) oacc[s][o] = (f32x4){0.f,0.f,0.f,0.f};

        #pragma unroll
        for (int ct = 0; ct < 16; ++ct){
            float bv = b1g[ct*16 + c16];
            f32x4 acc0 = {bv,bv,bv,bv}, acc1 = acc0;
            #pragma unroll
            for (int kt = 0; kt < 4; ++kt){
                short8 b = w1f[(kt*16 + ct)*64 + lane];
                acc0 = MFMA(a[0][kt], b, acc0, 0, 0, 0);
                acc1 = MFMA(a[1][kt], b, acc1, 0, 0, 0);
            }
            int colw = (ct & 1)*16 + c16;
            #pragma unroll
            for (int i = 0; i < 4; ++i){
                int row = g*4 + i;
                stg[row*40 + colw]      = f2bf(fmaxf(acc0[i], 0.f));
                stg[(16+row)*40 + colw] = f2bf(fmaxf(acc1[i], 0.f));
            }
            if (ct & 1){
                int kt2 = ct >> 1;
                short8 a20 = *(const short8*)(stg + c16*40 + g*8);
                short8 a21 = *(const short8*)(stg + (16 + c16)*40 + g*8);
                #pragma unroll
                for (int oc = 0; oc < 8; ++oc){
                    short8 b = w2f[(kt2*8 + oc)*64 + lane];
                    oacc[0][oc] = MFMA(a20, b, oacc[0][oc], 0, 0, 0);
                    oacc[1][oc] = MFMA(a21, b, oacc[1][oc], 0, 0, 0);
                }
            }
        }

        // ---- P-layout vector epilogues (bit-identical math, 16B stores) ----
        if (MODE == 0) {
            #pragma unroll
            for (int s = 0; s < 2; ++s){
                int rbase = t*32 + s*16 + g*4;
                #pragma unroll
                for (int i = 0; i < 4; ++i){
                    short8 v8;
                    #pragma unroll
                    for (int j = 0; j < 8; ++j)
                        v8[j] = (short)f2bf(oacc[s][j][i] + b2g[j*16 + c16]);
                    *(short8*)(out16 + (size_t)(rbase + i)*128 + c16*8) = v8;
                }
            }
        } else {
            int rbase = t*16 + g*4;
            #pragma unroll
            for (int i = 0; i < 4; ++i){
                float vf[8];
                short8 v8;
                #pragma unroll
                for (int j = 0; j < 8; ++j){
                    vf[j] = oacc[0][j][i] + oacc[1][j][i] + 2.f*b2g[j*16 + c16];
                    v8[j] = (short)f2bf(vf[j]);
                }
                size_t gb = (size_t)(rbase + i)*128 + c16*8;
                short8 h8 = *(const short8*)(hmaxb + gb);
                short8 m8;
                #pragma unroll
                for (int j = 0; j < 8; ++j)
                    m8[j] = (short)f2bf(fmaxf(bf2f((u16)h8[j]), vf[j]));
                *(short8*)(hmaxb + gb) = m8;
                *(short8*)(out16 + gb) = v8;
            }
        }
    }
}

// ============ edge hidden kernel: per node-aligned 32-edge tile ============
// Single-tile nodes plain-store ALL 256 positions (no zero-init needed);
// multi-tile nodes use pk_add atomics into rows pre-zeroed by mzero_kernel.
__global__ __launch_bounds__(512, 1)
void edgeh_kernel(const u16* __restrict__ sea, const u16* __restrict__ tnode,
                  const u16* __restrict__ tne, const int* __restrict__ sbase,
                  const float* __restrict__ W1p, const float* __restrict__ b1p,
                  u16* __restrict__ aggrH)
{
    __shared__ short8 w1f[8*64];   // B-frags: [cb][lane], B[k][n]: n=cb*32+(l&31), k=(l>>5)*8+j
    const int tid = threadIdx.x;
    if (tid < 8*64){
        int cb = tid >> 6, lane = tid & 63, half = lane >> 5, c = lane & 31;
        short8 v = (short8){0,0,0,0,0,0,0,0};
        if (half == 0){
            #pragma unroll
            for (int j = 0; j < 8; ++j) v[j] = (short)f2bf(W1p[j*256 + cb*32 + c]);
        } else {
            v[0] = (short)f2bf(b1p[cb*32 + c]);   // bias at k=8
        }
        w1f[tid] = v;
    }
    __syncthreads();

    const int wave = tid >> 6, lane = tid & 63;
    const int half = lane >> 5, c32 = lane & 31;
    const int wid0 = blockIdx.x*8 + wave;
    const int nwaves = gridDim.x*8;
    const short8 z = (short8){0,0,0,0,0,0,0,0};
    f32x16 zf16;
    #pragma unroll
    for (int i = 0; i < 16; ++i) zf16[i] = 0.f;

    for (int t = wid0; t < MAXT; t += nwaves){
        u16 tv = tne[t];
        int ne = tv & 0x7fff;
        if (ne == 0) continue;
        bool multi = (tv & 0x8000) != 0;
        int node = tnode[t];
        int sb   = sbase[t];

        bool val = c32 < ne;
        short8 a = z;
        if (half == 0){
            int e = sb + c32; if (e > EE-1) e = EE-1;
            short8 t0 = *(const short8*)(sea + (size_t)e*8);
            a = val ? t0 : z;
        } else {
            a[0] = val ? (short)0x3F80 : (short)0;   // bf16 1.0 validity flag
        }

        u64 base = (u64)(uintptr_t)(aggrH + (size_t)node*256);
        #pragma unroll
        for (int cb = 0; cb < 8; ++cb){
            short8 b = w1f[cb*64 + lane];
            f32x16 h = MFMA32(a, b, zf16, 0, 0, 0);
            float p0 = fmaxf(h[0],0.f) + fmaxf(h[1],0.f)
                     + fmaxf(h[2],0.f) + fmaxf(h[3],0.f);
            float p1 = fmaxf(h[4],0.f) + fmaxf(h[5],0.f)
                     + fmaxf(h[6],0.f) + fmaxf(h[7],0.f);
            float p2 = fmaxf(h[8],0.f) + fmaxf(h[9],0.f)
                     + fmaxf(h[10],0.f) + fmaxf(h[11],0.f);
            float p3 = fmaxf(h[12],0.f) + fmaxf(h[13],0.f)
                     + fmaxf(h[14],0.f) + fmaxf(h[15],0.f);
            float p = (p0 + p1) + (p2 + p3);
            p += __shfl_xor(p, 32, 64);
            float ph = __shfl_xor(p, 1, 64);
            if (half == 0 && !(c32 & 1)){
                u32 pk;
                asm("v_cvt_pk_bf16_f32 %0, %1, %2" : "=v"(pk) : "v"(p), "v"(ph));
                u64 addr = base + (u64)((cb*32 + c32)*2);
                if (multi){
                    asm volatile("global_atomic_pk_add_bf16 %0, %1, off"
                                 :: "v"(addr), "v"(pk) : "memory");
                } else {
                    *(u32*)(uintptr_t)addr = pk;
                }
            }
        }
    }
}

// mzero: zero aggrH rows of nodes needing init (multi-tile or deg==0).
__global__ __launch_bounds__(256)
void mzero_kernel(const int* __restrict__ mlist, const int* __restrict__ mcnt,
                  u16* __restrict__ aggrH){
    int total = mcnt[0] * 32;                 // 32 chunks of 16B per 512B row
    int stride = gridDim.x * blockDim.x;
    for (int i = blockIdx.x*blockDim.x + threadIdx.x; i < total; i += stride){
        int row = mlist[i >> 5], ch = i & 31;
        *(f32x4*)(aggrH + (size_t)row*256 + ch*8) = (f32x4){0.f,0.f,0.f,0.f};
    }
}

// ============ p2: aggr_bf = bf16( (aggrH @ W2m) * dinv + t*b2m ) ============
#define P2_SMEM 65536
__global__ __launch_bounds__(512)
void p2_kernel(const u16* __restrict__ aggrH, const u16* __restrict__ w2fg,
               const float* __restrict__ b2g, const int* __restrict__ deg,
               u16* __restrict__ aggr_bf)
{
    extern __shared__ char smem[];
    short8* w2f = (short8*)smem;
    const int tid = threadIdx.x;
    {
        const short8* s2 = (const short8*)w2fg;
        #pragma unroll
        for (int i = 0; i < 8; ++i) w2f[tid + i*512] = s2[tid + i*512];
    }
    __syncthreads();

    const int wave = tid >> 6, lane = tid & 63;
    const int g = lane >> 4, c16 = lane & 15;
    const int wid0 = blockIdx.x*8 + wave;
    const int nwaves = gridDim.x*8;
    const int ntiles = NN/32;

    for (int t = wid0; t < ntiles; t += nwaves){
        short8 a[2][8];
        #pragma unroll
        for (int sub = 0; sub < 2; ++sub){
            int r = t*32 + sub*16 + c16;
            #pragma unroll
            for (int kt = 0; kt < 8; ++kt)
                a[sub][kt] = *(const short8*)(aggrH + (size_t)r*256 + kt*32 + g*8);
        }
        f32x4 acc[2][8];
        #pragma unroll
        for (int s = 0; s < 2; ++s)
            #pragma unroll
            for (int o = 0; o < 8; ++o) acc[s][o] = (f32x4){0.f,0.f,0.f,0.f};
        #pragma unroll
        for (int kt = 0; kt < 8; ++kt){
            #pragma unroll
            for (int oc = 0; oc < 8; ++oc){
                short8 b = w2f[(kt*8 + oc)*64 + lane];
                acc[0][oc] = MFMA(a[0][kt], b, acc[0][oc], 0, 0, 0);
                acc[1][oc] = MFMA(a[1][kt], b, acc[1][oc], 0, 0, 0);
            }
        }
        #pragma unroll
        for (int s = 0; s < 2; ++s){
            int rbase = t*32 + s*16 + g*4;
            #pragma unroll
            for (int i = 0; i < 4; ++i){
                int d = deg[rbase + i];
                float tf = (d > 0) ? 1.f : 0.f;
                float dinv = 1.f / (float)((d < 1) ? 1 : d);
                short8 v8;
                #pragma unroll
                for (int j = 0; j < 8; ++j)
                    v8[j] = (short)f2bf(acc[s][j][i]*dinv + tf*b2g[j*16 + c16]);
                *(short8*)(aggr_bf + (size_t)(rbase + i)*128 + c16*8) = v8;
            }
        }
    }
}

// ============ csr: aggr_bf[n] += bf16( sum_e mhb[src_e] * dinv ) ============
__global__ __launch_bounds__(512)
void csr_kernel(const u16* __restrict__ mhb, const u16* __restrict__ ssrc,
                const int* __restrict__ offs, const int* __restrict__ deg,
                u16* __restrict__ aggr_bf)
{
    int w = (int)((blockIdx.x*blockDim.x + threadIdx.x) >> 6);
    int lane = threadIdx.x & 63;
    if (w >= NN) return;
    int o0 = offs[w], dn = deg[w];
    const u32* mh32 = (const u32*)mhb;
    float pl = 0.f, ph = 0.f;
    int k = 0;
    for (; k + 8 <= dn; k += 8){
        u32 v[8];
        #pragma unroll
        for (int j = 0; j < 8; ++j){
            int sc = ssrc[o0 + k + j];
            v[j] = mh32[(size_t)sc*64 + lane];
        }
        #pragma unroll
        for (int j = 0; j < 8; ++j){
            pl += bf2f((u16)(v[j] & 0xffffu));
            ph += bf2f((u16)(v[j] >> 16));
        }
    }
    for (; k < dn; ++k){
        int sc = ssrc[o0+k];
        u32 v = mh32[(size_t)sc*64 + lane];
        pl += bf2f((u16)(v & 0xffffu));
        ph += bf2f((u16)(v >> 16));
    }
    float dinv = 1.f / (float)((dn < 1) ? 1 : dn);
    u32* ab = (u32*)aggr_bf;
    u32 cur = ab[(size_t)w*64 + lane];
    float fl = bf2f((u16)(cur & 0xffffu)) + pl*dinv;
    float fh = bf2f((u16)(cur >> 16))    + ph*dinv;
    ab[(size_t)w*64 + lane] = (u32)f2bf(fl) | ((u32)f2bf(fh) << 16);
}

// ===================== setup kernels =====================
// prep: 18 blocks x 256 threads — block=(layer,row), row 0-7 = W1p, row 8 = b1p
__global__ __launch_bounds__(256)
void prep_kernel(const float* __restrict__ edge_w, const float* __restrict__ edge_b,
                 const float* __restrict__ msg_w1, const float* __restrict__ msg_b1,
                 float* __restrict__ W1p, float* __restrict__ b1p){
    int b = blockIdx.x;
    int l = b / 9, row = b % 9;
    int n = threadIdx.x;
    const float* w1 = msg_w1 + l*32768;
    const float* coef = (row < 8) ? (edge_w + row*128) : edge_b;
    float a0 = 0.f, a1 = 0.f, a2 = 0.f, a3 = 0.f;
    float a4 = 0.f, a5 = 0.f, a6 = 0.f, a7 = 0.f;
    #pragma unroll 2
    for (int c = 0; c < 128; c += 8){
        a0 += coef[c]   * w1[(c)*256 + n];
        a1 += coef[c+1] * w1[(c+1)*256 + n];
        a2 += coef[c+2] * w1[(c+2)*256 + n];
        a3 += coef[c+3] * w1[(c+3)*256 + n];
        a4 += coef[c+4] * w1[(c+4)*256 + n];
        a5 += coef[c+5] * w1[(c+5)*256 + n];
        a6 += coef[c+6] * w1[(c+6)*256 + n];
        a7 += coef[c+7] * w1[(c+7)*256 + n];
    }
    float s = ((a0+a1)+(a2+a3)) + ((a4+a5)+(a6+a7));
    if (row < 8) W1p[(l*8 + row)*256 + n] = s;
    else         b1p[l*256 + n] = s + msg_b1[l*256 + n];
}

// lift: 16 threads/node; thread th owns P-positions th*8+j (orig col j*16+th)
__global__ __launch_bounds__(256)
void lift_kernel(const float* __restrict__ x, const float* __restrict__ nw,
                 const float* __restrict__ nb, u16* __restrict__ hbf,
                 u16* __restrict__ hmaxb){
    __shared__ float nws[16*128];
    __shared__ float nbs[128];
    const int tid = threadIdx.x;
    for (int i = tid; i < 16*128; i += 256) nws[i] = nw[i];
    if (tid < 128) nbs[tid] = nb[tid];
    __syncthreads();

    int n = blockIdx.x*16 + (tid >> 4);
    int th = tid & 15;
    if (n >= NN) return;

    const float* xr = x + (size_t)n*16;
    float acc[8];
    #pragma unroll
    for (int j = 0; j < 8; ++j) acc[j] = nbs[j*16 + th];
    #pragma unroll
    for (int k = 0; k < 16; ++k){
        float xv = xr[k];
        #pragma unroll
        for (int j = 0; j < 8; ++j)
            acc[j] += xv * nws[k*128 + j*16 + th];
    }
    short8 v8;
    #pragma unroll
    for (int j = 0; j < 8; ++j) v8[j] = (short)f2bf(acc[j]);
    size_t gb = (size_t)n*128 + th*8;
    *(short8*)(hbf + gb) = v8;
    *(short8*)(hmaxb + gb) = v8;
}

__global__ void deg_kernel(const int* __restrict__ eidx, int* __restrict__ deg){
    int i = blockIdx.x*blockDim.x + threadIdx.x;
    for (; i < EE; i += gridDim.x*blockDim.x) atomicAdd(&deg[eidx[EE + i]], 1);
}

// ---- parallel scan, 3 stages ----
__global__ __launch_bounds__(256)
void scanA_kernel(const int* __restrict__ deg, int* __restrict__ partE,
                  int* __restrict__ partT){
    __shared__ int se[256], st[256];
    int t = threadIdx.x;
    int n = blockIdx.x*256 + t;
    int d = (n < NN) ? deg[n] : 0;
    se[t] = d; st[t] = (d + 31) >> 5;
    __syncthreads();
    for (int off = 128; off > 0; off >>= 1){
        if (t < off){ se[t] += se[t+off]; st[t] += st[t+off]; }
        __syncthreads();
    }
    if (t == 0){ partE[blockIdx.x] = se[0]; partT[blockIdx.x] = st[0]; }
}

__global__ __launch_bounds__(256)
void scanB_kernel(int* __restrict__ partE, int* __restrict__ partT){
    __shared__ int pe[256], pt[256];
    int t = threadIdx.x;
    pe[t] = (t < SCAN_B) ? partE[t] : 0;
    pt[t] = (t < SCAN_B) ? partT[t] : 0;
    __syncthreads();
    for (int off = 1; off < 256; off <<= 1){
        int ve = (t >= off) ? pe[t-off] : 0;
        int vt = (t >= off) ? pt[t-off] : 0;
        __syncthreads();
        pe[t] += ve; pt[t] += vt;
        __syncthreads();
    }
    if (t < SCAN_B){ partE[t] = pe[t]; partT[t] = pt[t]; }
}

__global__ __launch_bounds__(256)
void scanC_kernel(const int* __restrict__ deg, const int* __restrict__ partE,
                  const int* __restrict__ partT, int* __restrict__ offs,
                  u16* __restrict__ tnode, u16* __restrict__ tne,
                  int* __restrict__ sbase, int* __restrict__ mlist,
                  int* __restrict__ mcnt){
    __shared__ int se[256], st[256];
    int b = blockIdx.x, t = threadIdx.x;
    int n = b*256 + t;
    int d = (n < NN) ? deg[n] : 0;
    int nt = (d + 31) >> 5;
    se[t] = d; st[t] = nt;
    __syncthreads();
    for (int off = 1; off < 256; off <<= 1){
        int ve = (t >= off) ? se[t-off] : 0;
        int vt = (t >= off) ? st[t-off] : 0;
        __syncthreads();
        se[t] += ve; st[t] += vt;
        __syncthreads();
    }
    if (n < NN){
        int rune = ((b > 0) ? partE[b-1] : 0) + se[t] - d;
        int runt = ((b > 0) ? partT[b-1] : 0) + st[t] - nt;
        offs[n] = rune;
        // aggrH rows needing zero-init: multi-tile (atomic path) or deg==0
        if (nt > 1 || d == 0){
            int slot = atomicAdd(mcnt, 1);
            mlist[slot] = n;
        }
        u16 mflag = (nt > 1) ? (u16)0x8000 : (u16)0;
        for (int j = 0; j < nt; ++j){
            int tt = runt + j;
            tnode[tt] = (u16)n;
            int rem = d - 32*j;
            tne[tt] = (u16)(((rem > 32) ? 32 : rem) | mflag);
            sbase[tt] = rune + 32*j;
        }
    }
}

// counting-sort placement. R21: nontemporal loads for the streaming eattr /
// eidx reads keep them OUT of L2, so the scattered sea/ssrc target lines
// survive in-cache until fully covered -> write merging recovers (WRITE_SIZE
// was 64.8 MB for 11.5 MB payload due to read-stream pollution evictions).
__global__ void place_kernel(const float* __restrict__ eattr, const int* __restrict__ eidx,
                             const int* __restrict__ offs, int* __restrict__ cnt,
                             u16* __restrict__ sea, u16* __restrict__ ssrc){
    int e = blockIdx.x*blockDim.x + threadIdx.x;
    for (; e < EE; e += gridDim.x*blockDim.x){
        int d = __builtin_nontemporal_load(eidx + EE + e);
        int s = __builtin_nontemporal_load(eidx + e);
        int pos = offs[d] + atomicAdd(&cnt[d], 1);
        f32x4 a0 = __builtin_nontemporal_load((const f32x4*)(eattr + (size_t)e*8));
        f32x4 a1 = __builtin_nontemporal_load((const f32x4*)(eattr + (size_t)e*8 + 4));
        short8 v;
        #pragma unroll
        for (int j = 0; j < 4; ++j){
            v[j]   = (short)f2bf(a0[j]);
            v[4+j] = (short)f2bf(a1[j]);
        }
        *(short8*)(sea + (size_t)pos*8) = v;
        ssrc[pos] = (u16)s;
    }
}

// final: hmaxb is P-layout -> weight index via origcol(p)
__global__ void final_kernel(const u16* __restrict__ hmaxb, const float* __restrict__ fw,
                             const float* __restrict__ fb, float* __restrict__ out){
    int t = blockIdx.x*blockDim.x + threadIdx.x;
    if (t >= NN*4) return;
    int n = t >> 2, o = t & 3;
    float acc = fb[o];
    const u16* hr = hmaxb + (size_t)n*128;
    #pragma unroll 16
    for (int p = 0; p < 128; ++p) acc += bf2f(hr[p]) * fw[origcol(p)*4 + o];
    out[t] = acc;
}

extern "C" void kernel_launch(void* const* d_in, const int* in_sizes, int n_in,
                              void* d_out, int out_size, void* d_ws, size_t ws_size,
                              hipStream_t stream)
{
    (void)in_sizes; (void)n_in; (void)out_size; (void)ws_size;
    const float* x      = (const float*)d_in[0];
    const float* eattr  = (const float*)d_in[1];
    const int*   eidx   = (const int*)d_in[2];
    const float* node_w = (const float*)d_in[3];
    const float* node_b = (const float*)d_in[4];
    const float* edge_w = (const float*)d_in[5];
    const float* edge_b = (const float*)d_in[6];
    const float* msg_w1 = (const float*)d_in[7];
    const float* msg_b1 = (const float*)d_in[8];
    const float* msg_w2 = (const float*)d_in[9];
    const float* msg_b2 = (const float*)d_in[10];
    const float* upd_w1 = (const float*)d_in[11];
    const float* upd_b1 = (const float*)d_in[12];
    const float* upd_w2 = (const float*)d_in[13];
    const float* upd_b2 = (const float*)d_in[14];
    const float* fw     = (const float*)d_in[15];
    const float* fb     = (const float*)d_in[16];
    float* out = (float*)d_out;

    // workspace ~75.3 MB
    char* ws = (char*)d_ws;
    u16*   hbf     = (u16*)ws;  ws += (size_t)NN*128*2;     // 10.24 MB (P-layout)
    u16*   mhb     = (u16*)ws;  ws += (size_t)NN*128*2;     // 10.24 MB (P-layout)
    u16*   hmaxb   = (u16*)ws;  ws += (size_t)NN*128*2;     // 10.24 MB (P-layout)
    u16*   aggr_bf = (u16*)ws;  ws += (size_t)NN*128*2;     // 10.24 MB (P-layout)
    u16*   aggrH   = (u16*)ws;  ws += (size_t)NN*256*2;     // 20.48 MB
    u16*   sea     = (u16*)ws;  ws += (size_t)EE*8*2;       // 10.24 MB
    u16*   ssrc    = (u16*)ws;  ws += (size_t)EE*2;         //  1.28 MB
    u16*   mw1f    = (u16*)ws;  ws += (size_t)2*32768*2;    // packed msg_w1 frags (bf16)
    u16*   mw2f    = (u16*)ws;  ws += (size_t)2*32768*2;    // packed msg_w2 frags
    u16*   uw1f    = (u16*)ws;  ws += (size_t)2*32768*2;    // packed upd_w1 frags
    u16*   uw2f    = (u16*)ws;  ws += (size_t)2*32768*2;    // packed upd_w2 frags
    int*   deg     = (int*)ws;  ws += (size_t)NN*4;
    int*   offs    = (int*)ws;  ws += (size_t)NN*4;
    int*   cnt     = (int*)ws;  ws += (size_t)NN*4;
    int*   sbase   = (int*)ws;  ws += (size_t)MAXT*4;
    u16*   tnode   = (u16*)ws;  ws += (size_t)MAXT*2;
    u16*   tne     = (u16*)ws;  ws += (size_t)MAXT*2;
    int*   partE   = (int*)ws;  ws += (size_t)SCAN_B*4;
    int*   partT   = (int*)ws;  ws += (size_t)SCAN_B*4;
    int*   mlist   = (int*)ws;  ws += (size_t)NN*4;         //  0.16 MB
    int*   mcnt    = (int*)ws;  ws += 16;
    ws = (char*)(((uintptr_t)ws + 15) & ~(uintptr_t)15);
    float* W1p     = (float*)ws; ws += (size_t)2*8*256*4;
    float* b1p     = (float*)ws; ws += (size_t)2*256*4;

    hipFuncSetAttribute(reinterpret_cast<const void*>(&mlp_kernel<0>),
                        hipFuncAttributeMaxDynamicSharedMemorySize, SMEM_BYTES);
    hipFuncSetAttribute(reinterpret_cast<const void*>(&mlp_kernel<1>),
                        hipFuncAttributeMaxDynamicSharedMemorySize, SMEM_BYTES);
    hipFuncSetAttribute(reinterpret_cast<const void*>(&p2_kernel),
                        hipFuncAttributeMaxDynamicSharedMemorySize, P2_SMEM);

    hipMemsetAsync(deg, 0, (size_t)NN*4, stream);
    hipMemsetAsync(cnt, 0, (size_t)NN*4, stream);
    hipMemsetAsync(tne, 0, (size_t)MAXT*2, stream);
    hipMemsetAsync(mcnt, 0, 16, stream);
    deg_kernel<<<1024, 256, 0, stream>>>(eidx, deg);
    scanA_kernel<<<SCAN_B, 256, 0, stream>>>(deg, partE, partT);
    scanB_kernel<<<1, 256, 0, stream>>>(partE, partT);
    scanC_kernel<<<SCAN_B, 256, 0, stream>>>(deg, partE, partT, offs, tnode, tne,
                                             sbase, mlist, mcnt);
    place_kernel<<<2048, 256, 0, stream>>>(eattr, eidx, offs, cnt, sea, ssrc);
    lift_kernel<<<2500, 256, 0, stream>>>(x, node_w, node_b, hbf, hmaxb);
    prep_kernel<<<18, 256, 0, stream>>>(edge_w, edge_b, msg_w1, msg_b1, W1p, b1p);
    packall_kernel<<<1024, 256, 0, stream>>>(msg_w1, msg_w2, upd_w1, upd_w2,
                                             mw1f, mw2f, uw1f, uw2f);

    for (int l = 0; l < 2; ++l){
        // Mh = bf16(MLP_msg(h) + b2m) per node  (P-layout out)
        mlp_kernel<0><<<256, 512, SMEM_BYTES, stream>>>(
            hbf, nullptr,
            mw1f + l*32768, msg_b1 + l*256, mw2f + l*32768, msg_b2 + l*128,
            mhb, nullptr, NN/32);
        // zero only aggrH rows needing init (multi-tile or deg==0 nodes)
        mzero_kernel<<<64, 256, 0, stream>>>(mlist, mcnt, aggrH);
        // hidden-space edge aggregation
        edgeh_kernel<<<1024, 512, 0, stream>>>(sea, tnode, tne, sbase,
                                               W1p + l*2048, b1p + l*256, aggrH);
        // aggr_bf = bf16((aggrH @ W2m)*dinv + t*b2m)  (P-layout out)
        p2_kernel<<<256, 512, P2_SMEM, stream>>>(aggrH, mw2f + l*32768,
                                                 msg_b2 + l*128, deg, aggr_bf);
        // aggr_bf += bf16(sum Mh[src] * dinv)
        csr_kernel<<<5000, 512, 0, stream>>>(mhb, ssrc, offs, deg, aggr_bf);
        // h' = MLP_upd(h) + MLP_upd(aggr); hmaxb, hbf update  (P-layout)
        mlp_kernel<1><<<256, 512, SMEM_BYTES, stream>>>(
            hbf, aggr_bf,
            uw1f + l*32768, upd_b1 + l*256, uw2f + l*32768, upd_b2 + l*128,
            hbf, hmaxb, NN/16);
    }

    final_kernel<<<625, 256, 0, stream>>>(hmaxb, fw, fb, out);
}

// Round 22
// 385.310 us; speedup vs baseline: 1.0166x; 1.0166x over previous
//
#include <hip/hip_runtime.h>

#define NN 40000
#define EE 640000
#define MAXT 58752   // >= (EE + 31*NN)/32, exact worst-case padded-tile bound
#define SCAN_B 157   // ceil(NN/256)

typedef unsigned short u16;
typedef unsigned int u32;
typedef unsigned long long u64;
typedef __attribute__((ext_vector_type(8))) short short8;
typedef __attribute__((ext_vector_type(4))) float f32x4;
typedef __attribute__((ext_vector_type(16))) float f32x16;

__device__ __forceinline__ float bf2f(u16 b){ u32 u=((u32)b)<<16; float f; __builtin_memcpy(&f,&u,4); return f; }
__device__ __forceinline__ u16 f2bf(float f){ u32 u; __builtin_memcpy(&u,&f,4); u = (u + 0x7fffu + ((u>>16)&1u))>>16; return (u16)u; }

// P-layout: 128-wide node buffers store column c at position
// pos(c) = ((c&15)<<3)|(c>>4); orig(p) = ((p&7)<<4)|(p>>3).
__device__ __forceinline__ int origcol(int p){ return ((p & 7) << 4) | (p >> 3); }

#define MFMA __builtin_amdgcn_mfma_f32_16x16x32_bf16
#define MFMA32 __builtin_amdgcn_mfma_f32_32x32x16_bf16

// ---- pack ALL 8 weight matrices (f32) -> bf16 B-fragment order, one launch ----
__global__ __launch_bounds__(256)
void packall_kernel(const float* __restrict__ mw1, const float* __restrict__ mw2,
                    const float* __restrict__ uw1, const float* __restrict__ uw2,
                    u16* __restrict__ dm1, u16* __restrict__ dm2,
                    u16* __restrict__ du1, u16* __restrict__ du2){
    int idx = blockIdx.x*blockDim.x + threadIdx.x;   // 4 * 65536
    if (idx >= 4*65536) return;
    int a = idx >> 16, rem = idx & 65535;
    int l = rem >> 15, e = rem & 32767;
    const float* src; u16* dst;
    if (a == 0){ src = mw1; dst = dm1; }
    else if (a == 1){ src = uw1; dst = du1; }
    else if (a == 2){ src = mw2; dst = dm2; }
    else { src = uw2; dst = du2; }
    float v; int o;
    if (a < 2){
        int k = e >> 8, n = e & 255;          // k = NEW k (P-layout position)
        v = src[l*32768 + origcol(k)*256 + n];
        o = (((k>>5)*16 + (n>>4))*64 + ((k>>3)&3)*16 + (n&15))*8 + (k&7);
    } else {
        int k = e >> 7, n = e & 127;
        v = src[l*32768 + e];
        o = (((k>>5)*8 + (n>>4))*64 + ((k>>3)&3)*16 + (n&15))*8 + (k&7);
    }
    dst[l*32768 + o] = f2bf(v);
}

// ================== node-side fused MLP (modes 0/1) ==================
// LDS: w1f 64KB @0, w2f 64KB @65536, stg 20KB @131072 -> 151552
#define SMEM_BYTES 151552

template<int MODE>
__global__ __launch_bounds__(512, 1)
void mlp_kernel(const u16* __restrict__ xa, const u16* __restrict__ xb,
                const u16* __restrict__ w1fg, const float* __restrict__ b1g,
                const u16* __restrict__ w2fg, const float* __restrict__ b2g,
                u16* __restrict__ out16, u16* __restrict__ hmaxb, int ntiles)
{
    extern __shared__ char smem[];
    short8* w1f = (short8*)smem;
    short8* w2f = (short8*)(smem + 65536);
    u16* stg_all = (u16*)(smem + 131072);

    const int tid = threadIdx.x;
    {   // fast prologue: 128KB linear copy from pre-packed fragments
        const short8* s1 = (const short8*)w1fg;
        const short8* s2 = (const short8*)w2fg;
        #pragma unroll
        for (int i = 0; i < 8; ++i) w1f[tid + i*512] = s1[tid + i*512];
        #pragma unroll
        for (int i = 0; i < 8; ++i) w2f[tid + i*512] = s2[tid + i*512];
    }
    __syncthreads();

    const int wave = tid >> 6, lane = tid & 63;
    const int g = lane >> 4, c16 = lane & 15;
    u16* stg = stg_all + wave*1280;   // 32 rows * 40 u16

    const int wid0 = blockIdx.x*8 + wave;
    const int nwaves = gridDim.x*8;

    for (int t = wid0; t < ntiles; t += nwaves) {
        short8 a[2][4];
        if (MODE == 0) {
            #pragma unroll
            for (int sub = 0; sub < 2; ++sub){
                int r = t*32 + sub*16 + c16;
                #pragma unroll
                for (int kt = 0; kt < 4; ++kt)
                    a[sub][kt] = *(const short8*)(xa + r*128 + kt*32 + g*8);
            }
        } else {
            int r = t*16 + c16;
            #pragma unroll
            for (int kt = 0; kt < 4; ++kt){
                a[0][kt] = *(const short8*)(xa + r*128 + kt*32 + g*8);
                a[1][kt] = *(const short8*)(xb + r*128 + kt*32 + g*8);
            }
        }

        f32x4 oacc[2][8];
        #pragma unroll
        for (int s = 0; s < 2; ++s)
            #pragma unroll
            for (int o = 0; o < 8; ++o) oacc[s][o] = (f32x4){0.f,0.f,0.f,0.f};

        #pragma unroll
        for (int ct = 0; ct < 16; ++ct){
            float bv = b1g[ct*16 + c16];
            f32x4 acc0 = {bv,bv,bv,bv}, acc1 = acc0;
            #pragma unroll
            for (int kt = 0; kt < 4; ++kt){
                short8 b = w1f[(kt*16 + ct)*64 + lane];
                acc0 = MFMA(a[0][kt], b, acc0, 0, 0, 0);
                acc1 = MFMA(a[1][kt], b, acc1, 0, 0, 0);
            }
            int colw = (ct & 1)*16 + c16;
            #pragma unroll
            for (int i = 0; i < 4; ++i){
                int row = g*4 + i;
                stg[row*40 + colw]      = f2bf(fmaxf(acc0[i], 0.f));
                stg[(16+row)*40 + colw] = f2bf(fmaxf(acc1[i], 0.f));
            }
            if (ct & 1){
                int kt2 = ct >> 1;
                short8 a20 = *(const short8*)(stg + c16*40 + g*8);
                short8 a21 = *(const short8*)(stg + (16 + c16)*40 + g*8);
                #pragma unroll
                for (int oc = 0; oc < 8; ++oc){
                    short8 b = w2f[(kt2*8 + oc)*64 + lane];
                    oacc[0][oc] = MFMA(a20, b, oacc[0][oc], 0, 0, 0);
                    oacc[1][oc] = MFMA(a21, b, oacc[1][oc], 0, 0, 0);
                }
            }
        }

        // ---- P-layout vector epilogues (bit-identical math, 16B stores) ----
        if (MODE == 0) {
            #pragma unroll
            for (int s = 0; s < 2; ++s){
                int rbase = t*32 + s*16 + g*4;
                #pragma unroll
                for (int i = 0; i < 4; ++i){
                    short8 v8;
                    #pragma unroll
                    for (int j = 0; j < 8; ++j)
                        v8[j] = (short)f2bf(oacc[s][j][i] + b2g[j*16 + c16]);
                    *(short8*)(out16 + (size_t)(rbase + i)*128 + c16*8) = v8;
                }
            }
        } else {
            int rbase = t*16 + g*4;
            #pragma unroll
            for (int i = 0; i < 4; ++i){
                float vf[8];
                short8 v8;
                #pragma unroll
                for (int j = 0; j < 8; ++j){
                    vf[j] = oacc[0][j][i] + oacc[1][j][i] + 2.f*b2g[j*16 + c16];
                    v8[j] = (short)f2bf(vf[j]);
                }
                size_t gb = (size_t)(rbase + i)*128 + c16*8;
                short8 h8 = *(const short8*)(hmaxb + gb);
                short8 m8;
                #pragma unroll
                for (int j = 0; j < 8; ++j)
                    m8[j] = (short)f2bf(fmaxf(bf2f((u16)h8[j]), vf[j]));
                *(short8*)(hmaxb + gb) = m8;
                *(short8*)(out16 + gb) = v8;
            }
        }
    }
}

// ============ edge hidden kernel: per node-aligned 32-edge tile ============
// Single-tile nodes plain-store ALL 256 positions (no zero-init needed);
// multi-tile nodes use pk_add atomics into rows pre-zeroed by mzero_kernel.
__global__ __launch_bounds__(512, 1)
void edgeh_kernel(const u16* __restrict__ sea, const u16* __restrict__ tnode,
                  const u16* __restrict__ tne, const int* __restrict__ sbase,
                  const float* __restrict__ W1p, const float* __restrict__ b1p,
                  u16* __restrict__ aggrH)
{
    __shared__ short8 w1f[8*64];   // B-frags: [cb][lane], B[k][n]: n=cb*32+(l&31), k=(l>>5)*8+j
    const int tid = threadIdx.x;
    if (tid < 8*64){
        int cb = tid >> 6, lane = tid & 63, half = lane >> 5, c = lane & 31;
        short8 v = (short8){0,0,0,0,0,0,0,0};
        if (half == 0){
            #pragma unroll
            for (int j = 0; j < 8; ++j) v[j] = (short)f2bf(W1p[j*256 + cb*32 + c]);
        } else {
            v[0] = (short)f2bf(b1p[cb*32 + c]);   // bias at k=8
        }
        w1f[tid] = v;
    }
    __syncthreads();

    const int wave = tid >> 6, lane = tid & 63;
    const int half = lane >> 5, c32 = lane & 31;
    const int wid0 = blockIdx.x*8 + wave;
    const int nwaves = gridDim.x*8;
    const short8 z = (short8){0,0,0,0,0,0,0,0};
    f32x16 zf16;
    #pragma unroll
    for (int i = 0; i < 16; ++i) zf16[i] = 0.f;

    for (int t = wid0; t < MAXT; t += nwaves){
        u16 tv = tne[t];
        int ne = tv & 0x7fff;
        if (ne == 0) continue;
        bool multi = (tv & 0x8000) != 0;
        int node = tnode[t];
        int sb   = sbase[t];

        bool val = c32 < ne;
        short8 a = z;
        if (half == 0){
            int e = sb + c32; if (e > EE-1) e = EE-1;
            short8 t0 = *(const short8*)(sea + (size_t)e*8);
            a = val ? t0 : z;
        } else {
            a[0] = val ? (short)0x3F80 : (short)0;   // bf16 1.0 validity flag
        }

        u64 base = (u64)(uintptr_t)(aggrH + (size_t)node*256);
        #pragma unroll
        for (int cb = 0; cb < 8; ++cb){
            short8 b = w1f[cb*64 + lane];
            f32x16 h = MFMA32(a, b, zf16, 0, 0, 0);
            float p0 = fmaxf(h[0],0.f) + fmaxf(h[1],0.f)
                     + fmaxf(h[2],0.f) + fmaxf(h[3],0.f);
            float p1 = fmaxf(h[4],0.f) + fmaxf(h[5],0.f)
                     + fmaxf(h[6],0.f) + fmaxf(h[7],0.f);
            float p2 = fmaxf(h[8],0.f) + fmaxf(h[9],0.f)
                     + fmaxf(h[10],0.f) + fmaxf(h[11],0.f);
            float p3 = fmaxf(h[12],0.f) + fmaxf(h[13],0.f)
                     + fmaxf(h[14],0.f) + fmaxf(h[15],0.f);
            float p = (p0 + p1) + (p2 + p3);
            p += __shfl_xor(p, 32, 64);
            float ph = __shfl_xor(p, 1, 64);
            if (half == 0 && !(c32 & 1)){
                u32 pk;
                asm("v_cvt_pk_bf16_f32 %0, %1, %2" : "=v"(pk) : "v"(p), "v"(ph));
                u64 addr = base + (u64)((cb*32 + c32)*2);
                if (multi){
                    asm volatile("global_atomic_pk_add_bf16 %0, %1, off"
                                 :: "v"(addr), "v"(pk) : "memory");
                } else {
                    *(u32*)(uintptr_t)addr = pk;
                }
            }
        }
    }
}

// mzero: zero aggrH rows of nodes needing init (multi-tile or deg==0).
__global__ __launch_bounds__(256)
void mzero_kernel(const int* __restrict__ mlist, const int* __restrict__ mcnt,
                  u16* __restrict__ aggrH){
    int total = mcnt[0] * 32;                 // 32 chunks of 16B per 512B row
    int stride = gridDim.x * blockDim.x;
    for (int i = blockIdx.x*blockDim.x + threadIdx.x; i < total; i += stride){
        int row = mlist[i >> 5], ch = i & 31;
        *(f32x4*)(aggrH + (size_t)row*256 + ch*8) = (f32x4){0.f,0.f,0.f,0.f};
    }
}

// ============ p2: aggr_bf = bf16( (aggrH @ W2m) * dinv + t*b2m ) ============
#define P2_SMEM 65536
__global__ __launch_bounds__(512)
void p2_kernel(const u16* __restrict__ aggrH, const u16* __restrict__ w2fg,
               const float* __restrict__ b2g, const int* __restrict__ deg,
               u16* __restrict__ aggr_bf)
{
    extern __shared__ char smem[];
    short8* w2f = (short8*)smem;
    const int tid = threadIdx.x;
    {
        const short8* s2 = (const short8*)w2fg;
        #pragma unroll
        for (int i = 0; i < 8; ++i) w2f[tid + i*512] = s2[tid + i*512];
    }
    __syncthreads();

    const int wave = tid >> 6, lane = tid & 63;
    const int g = lane >> 4, c16 = lane & 15;
    const int wid0 = blockIdx.x*8 + wave;
    const int nwaves = gridDim.x*8;
    const int ntiles = NN/32;

    for (int t = wid0; t < ntiles; t += nwaves){
        short8 a[2][8];
        #pragma unroll
        for (int sub = 0; sub < 2; ++sub){
            int r = t*32 + sub*16 + c16;
            #pragma unroll
            for (int kt = 0; kt < 8; ++kt)
                a[sub][kt] = *(const short8*)(aggrH + (size_t)r*256 + kt*32 + g*8);
        }
        f32x4 acc[2][8];
        #pragma unroll
        for (int s = 0; s < 2; ++s)
            #pragma unroll
            for (int o = 0; o < 8; ++o) acc[s][o] = (f32x4){0.f,0.f,0.f,0.f};
        #pragma unroll
        for (int kt = 0; kt < 8; ++kt){
            #pragma unroll
            for (int oc = 0; oc < 8; ++oc){
                short8 b = w2f[(kt*8 + oc)*64 + lane];
                acc[0][oc] = MFMA(a[0][kt], b, acc[0][oc], 0, 0, 0);
                acc[1][oc] = MFMA(a[1][kt], b, acc[1][oc], 0, 0, 0);
            }
        }
        #pragma unroll
        for (int s = 0; s < 2; ++s){
            int rbase = t*32 + s*16 + g*4;
            #pragma unroll
            for (int i = 0; i < 4; ++i){
                int d = deg[rbase + i];
                float tf = (d > 0) ? 1.f : 0.f;
                float dinv = 1.f / (float)((d < 1) ? 1 : d);
                short8 v8;
                #pragma unroll
                for (int j = 0; j < 8; ++j)
                    v8[j] = (short)f2bf(acc[s][j][i]*dinv + tf*b2g[j*16 + c16]);
                *(short8*)(aggr_bf + (size_t)(rbase + i)*128 + c16*8) = v8;
            }
        }
    }
}

// ============ csr: aggr_bf[n] += bf16( sum_e mhb[src_e] * dinv ) ============
__global__ __launch_bounds__(512)
void csr_kernel(const u16* __restrict__ mhb, const u16* __restrict__ ssrc,
                const int* __restrict__ offs, const int* __restrict__ deg,
                u16* __restrict__ aggr_bf)
{
    int w = (int)((blockIdx.x*blockDim.x + threadIdx.x) >> 6);
    int lane = threadIdx.x & 63;
    if (w >= NN) return;
    int o0 = offs[w], dn = deg[w];
    const u32* mh32 = (const u32*)mhb;
    float pl = 0.f, ph = 0.f;
    int k = 0;
    for (; k + 8 <= dn; k += 8){
        u32 v[8];
        #pragma unroll
        for (int j = 0; j < 8; ++j){
            int sc = ssrc[o0 + k + j];
            v[j] = mh32[(size_t)sc*64 + lane];
        }
        #pragma unroll
        for (int j = 0; j < 8; ++j){
            pl += bf2f((u16)(v[j] & 0xffffu));
            ph += bf2f((u16)(v[j] >> 16));
        }
    }
    for (; k < dn; ++k){
        int sc = ssrc[o0+k];
        u32 v = mh32[(size_t)sc*64 + lane];
        pl += bf2f((u16)(v & 0xffffu));
        ph += bf2f((u16)(v >> 16));
    }
    float dinv = 1.f / (float)((dn < 1) ? 1 : dn);
    u32* ab = (u32*)aggr_bf;
    u32 cur = ab[(size_t)w*64 + lane];
    float fl = bf2f((u16)(cur & 0xffffu)) + pl*dinv;
    float fh = bf2f((u16)(cur >> 16))    + ph*dinv;
    ab[(size_t)w*64 + lane] = (u32)f2bf(fl) | ((u32)f2bf(fh) << 16);
}

// ===================== setup kernels =====================
// prep: 18 blocks x 256 threads — block=(layer,row), row 0-7 = W1p, row 8 = b1p
__global__ __launch_bounds__(256)
void prep_kernel(const float* __restrict__ edge_w, const float* __restrict__ edge_b,
                 const float* __restrict__ msg_w1, const float* __restrict__ msg_b1,
                 float* __restrict__ W1p, float* __restrict__ b1p){
    int b = blockIdx.x;
    int l = b / 9, row = b % 9;
    int n = threadIdx.x;
    const float* w1 = msg_w1 + l*32768;
    const float* coef = (row < 8) ? (edge_w + row*128) : edge_b;
    float a0 = 0.f, a1 = 0.f, a2 = 0.f, a3 = 0.f;
    float a4 = 0.f, a5 = 0.f, a6 = 0.f, a7 = 0.f;
    #pragma unroll 2
    for (int c = 0; c < 128; c += 8){
        a0 += coef[c]   * w1[(c)*256 + n];
        a1 += coef[c+1] * w1[(c+1)*256 + n];
        a2 += coef[c+2] * w1[(c+2)*256 + n];
        a3 += coef[c+3] * w1[(c+3)*256 + n];
        a4 += coef[c+4] * w1[(c+4)*256 + n];
        a5 += coef[c+5] * w1[(c+5)*256 + n];
        a6 += coef[c+6] * w1[(c+6)*256 + n];
        a7 += coef[c+7] * w1[(c+7)*256 + n];
    }
    float s = ((a0+a1)+(a2+a3)) + ((a4+a5)+(a6+a7));
    if (row < 8) W1p[(l*8 + row)*256 + n] = s;
    else         b1p[l*256 + n] = s + msg_b1[l*256 + n];
}

// lift: 16 threads/node; thread th owns P-positions th*8+j (orig col j*16+th)
__global__ __launch_bounds__(256)
void lift_kernel(const float* __restrict__ x, const float* __restrict__ nw,
                 const float* __restrict__ nb, u16* __restrict__ hbf,
                 u16* __restrict__ hmaxb){
    __shared__ float nws[16*128];
    __shared__ float nbs[128];
    const int tid = threadIdx.x;
    for (int i = tid; i < 16*128; i += 256) nws[i] = nw[i];
    if (tid < 128) nbs[tid] = nb[tid];
    __syncthreads();

    int n = blockIdx.x*16 + (tid >> 4);
    int th = tid & 15;
    if (n >= NN) return;

    const float* xr = x + (size_t)n*16;
    float acc[8];
    #pragma unroll
    for (int j = 0; j < 8; ++j) acc[j] = nbs[j*16 + th];
    #pragma unroll
    for (int k = 0; k < 16; ++k){
        float xv = xr[k];
        #pragma unroll
        for (int j = 0; j < 8; ++j)
            acc[j] += xv * nws[k*128 + j*16 + th];
    }
    short8 v8;
    #pragma unroll
    for (int j = 0; j < 8; ++j) v8[j] = (short)f2bf(acc[j]);
    size_t gb = (size_t)n*128 + th*8;
    *(short8*)(hbf + gb) = v8;
    *(short8*)(hmaxb + gb) = v8;
}

__global__ void deg_kernel(const int* __restrict__ eidx, int* __restrict__ deg){
    int i = blockIdx.x*blockDim.x + threadIdx.x;
    for (; i < EE; i += gridDim.x*blockDim.x) atomicAdd(&deg[eidx[EE + i]], 1);
}

// ---- parallel scan, 3 stages ----
__global__ __launch_bounds__(256)
void scanA_kernel(const int* __restrict__ deg, int* __restrict__ partE,
                  int* __restrict__ partT){
    __shared__ int se[256], st[256];
    int t = threadIdx.x;
    int n = blockIdx.x*256 + t;
    int d = (n < NN) ? deg[n] : 0;
    se[t] = d; st[t] = (d + 31) >> 5;
    __syncthreads();
    for (int off = 128; off > 0; off >>= 1){
        if (t < off){ se[t] += se[t+off]; st[t] += st[t+off]; }
        __syncthreads();
    }
    if (t == 0){ partE[blockIdx.x] = se[0]; partT[blockIdx.x] = st[0]; }
}

__global__ __launch_bounds__(256)
void scanB_kernel(int* __restrict__ partE, int* __restrict__ partT){
    __shared__ int pe[256], pt[256];
    int t = threadIdx.x;
    pe[t] = (t < SCAN_B) ? partE[t] : 0;
    pt[t] = (t < SCAN_B) ? partT[t] : 0;
    __syncthreads();
    for (int off = 1; off < 256; off <<= 1){
        int ve = (t >= off) ? pe[t-off] : 0;
        int vt = (t >= off) ? pt[t-off] : 0;
        __syncthreads();
        pe[t] += ve; pt[t] += vt;
        __syncthreads();
    }
    if (t < SCAN_B){ partE[t] = pe[t]; partT[t] = pt[t]; }
}

__global__ __launch_bounds__(256)
void scanC_kernel(const int* __restrict__ deg, const int* __restrict__ partE,
                  const int* __restrict__ partT, int* __restrict__ offs,
                  u16* __restrict__ tnode, u16* __restrict__ tne,
                  int* __restrict__ sbase, int* __restrict__ mlist,
                  int* __restrict__ mcnt){
    __shared__ int se[256], st[256];
    int b = blockIdx.x, t = threadIdx.x;
    int n = b*256 + t;
    int d = (n < NN) ? deg[n] : 0;
    int nt = (d + 31) >> 5;
    se[t] = d; st[t] = nt;
    __syncthreads();
    for (int off = 1; off < 256; off <<= 1){
        int ve = (t >= off) ? se[t-off] : 0;
        int vt = (t >= off) ? st[t-off] : 0;
        __syncthreads();
        se[t] += ve; st[t] += vt;
        __syncthreads();
    }
    if (n < NN){
        int rune = ((b > 0) ? partE[b-1] : 0) + se[t] - d;
        int runt = ((b > 0) ? partT[b-1] : 0) + st[t] - nt;
        offs[n] = rune;
        // aggrH rows needing zero-init: multi-tile (atomic path) or deg==0
        if (nt > 1 || d == 0){
            int slot = atomicAdd(mcnt, 1);
            mlist[slot] = n;
        }
        u16 mflag = (nt > 1) ? (u16)0x8000 : (u16)0;
        for (int j = 0; j < nt; ++j){
            int tt = runt + j;
            tnode[tt] = (u16)n;
            int rem = d - 32*j;
            tne[tt] = (u16)(((rem > 32) ? 32 : rem) | mflag);
            sbase[tt] = rune + 32*j;
        }
    }
}

// counting-sort placement (R13-proven single-pass version; R21's nontemporal
// variant regressed — scatter amplification is cross-XCD-structural, at floor)
__global__ void place_kernel(const float* __restrict__ eattr, const int* __restrict__ eidx,
                             const int* __restrict__ offs, int* __restrict__ cnt,
                             u16* __restrict__ sea, u16* __restrict__ ssrc){
    int e = blockIdx.x*blockDim.x + threadIdx.x;
    for (; e < EE; e += gridDim.x*blockDim.x){
        int d = eidx[EE + e];
        int pos = offs[d] + atomicAdd(&cnt[d], 1);
        f32x4 a0 = *(const f32x4*)(eattr + (size_t)e*8);
        f32x4 a1 = *(const f32x4*)(eattr + (size_t)e*8 + 4);
        short8 v;
        #pragma unroll
        for (int j = 0; j < 4; ++j){
            v[j]   = (short)f2bf(a0[j]);
            v[4+j] = (short)f2bf(a1[j]);
        }
        *(short8*)(sea + (size_t)pos*8) = v;
        ssrc[pos] = (u16)eidx[e];
    }
}

// final: hmaxb is P-layout -> weight index via origcol(p)
__global__ void final_kernel(const u16* __restrict__ hmaxb, const float* __restrict__ fw,
                             const float* __restrict__ fb, float* __restrict__ out){
    int t = blockIdx.x*blockDim.x + threadIdx.x;
    if (t >= NN*4) return;
    int n = t >> 2, o = t & 3;
    float acc = fb[o];
    const u16* hr = hmaxb + (size_t)n*128;
    #pragma unroll 16
    for (int p = 0; p < 128; ++p) acc += bf2f(hr[p]) * fw[origcol(p)*4 + o];
    out[t] = acc;
}

extern "C" void kernel_launch(void* const* d_in, const int* in_sizes, int n_in,
                              void* d_out, int out_size, void* d_ws, size_t ws_size,
                              hipStream_t stream)
{
    (void)in_sizes; (void)n_in; (void)out_size; (void)ws_size;
    const float* x      = (const float*)d_in[0];
    const float* eattr  = (const float*)d_in[1];
    const int*   eidx   = (const int*)d_in[2];
    const float* node_w = (const float*)d_in[3];
    const float* node_b = (const float*)d_in[4];
    const float* edge_w = (const float*)d_in[5];
    const float* edge_b = (const float*)d_in[6];
    const float* msg_w1 = (const float*)d_in[7];
    const float* msg_b1 = (const float*)d_in[8];
    const float* msg_w2 = (const float*)d_in[9];
    const float* msg_b2 = (const float*)d_in[10];
    const float* upd_w1 = (const float*)d_in[11];
    const float* upd_b1 = (const float*)d_in[12];
    const float* upd_w2 = (const float*)d_in[13];
    const float* upd_b2 = (const float*)d_in[14];
    const float* fw     = (const float*)d_in[15];
    const float* fb     = (const float*)d_in[16];
    float* out = (float*)d_out;

    // workspace ~75.3 MB
    char* ws = (char*)d_ws;
    u16*   hbf     = (u16*)ws;  ws += (size_t)NN*128*2;     // 10.24 MB (P-layout)
    u16*   mhb     = (u16*)ws;  ws += (size_t)NN*128*2;     // 10.24 MB (P-layout)
    u16*   hmaxb   = (u16*)ws;  ws += (size_t)NN*128*2;     // 10.24 MB (P-layout)
    u16*   aggr_bf = (u16*)ws;  ws += (size_t)NN*128*2;     // 10.24 MB (P-layout)
    u16*   aggrH   = (u16*)ws;  ws += (size_t)NN*256*2;     // 20.48 MB
    u16*   sea     = (u16*)ws;  ws += (size_t)EE*8*2;       // 10.24 MB
    u16*   ssrc    = (u16*)ws;  ws += (size_t)EE*2;         //  1.28 MB
    u16*   mw1f    = (u16*)ws;  ws += (size_t)2*32768*2;    // packed msg_w1 frags (bf16)
    u16*   mw2f    = (u16*)ws;  ws += (size_t)2*32768*2;    // packed msg_w2 frags
    u16*   uw1f    = (u16*)ws;  ws += (size_t)2*32768*2;    // packed upd_w1 frags
    u16*   uw2f    = (u16*)ws;  ws += (size_t)2*32768*2;    // packed upd_w2 frags
    int*   deg     = (int*)ws;  ws += (size_t)NN*4;
    int*   offs    = (int*)ws;  ws += (size_t)NN*4;
    int*   cnt     = (int*)ws;  ws += (size_t)NN*4;
    int*   sbase   = (int*)ws;  ws += (size_t)MAXT*4;
    u16*   tnode   = (u16*)ws;  ws += (size_t)MAXT*2;
    u16*   tne     = (u16*)ws;  ws += (size_t)MAXT*2;
    int*   partE   = (int*)ws;  ws += (size_t)SCAN_B*4;
    int*   partT   = (int*)ws;  ws += (size_t)SCAN_B*4;
    int*   mlist   = (int*)ws;  ws += (size_t)NN*4;         //  0.16 MB
    int*   mcnt    = (int*)ws;  ws += 16;
    ws = (char*)(((uintptr_t)ws + 15) & ~(uintptr_t)15);
    float* W1p     = (float*)ws; ws += (size_t)2*8*256*4;
    float* b1p     = (float*)ws; ws += (size_t)2*256*4;

    hipFuncSetAttribute(reinterpret_cast<const void*>(&mlp_kernel<0>),
                        hipFuncAttributeMaxDynamicSharedMemorySize, SMEM_BYTES);
    hipFuncSetAttribute(reinterpret_cast<const void*>(&mlp_kernel<1>),
                        hipFuncAttributeMaxDynamicSharedMemorySize, SMEM_BYTES);
    hipFuncSetAttribute(reinterpret_cast<const void*>(&p2_kernel),
                        hipFuncAttributeMaxDynamicSharedMemorySize, P2_SMEM);

    hipMemsetAsync(deg, 0, (size_t)NN*4, stream);
    hipMemsetAsync(cnt, 0, (size_t)NN*4, stream);
    hipMemsetAsync(tne, 0, (size_t)MAXT*2, stream);
    hipMemsetAsync(mcnt, 0, 16, stream);
    deg_kernel<<<1024, 256, 0, stream>>>(eidx, deg);
    scanA_kernel<<<SCAN_B, 256, 0, stream>>>(deg, partE, partT);
    scanB_kernel<<<1, 256, 0, stream>>>(partE, partT);
    scanC_kernel<<<SCAN_B, 256, 0, stream>>>(deg, partE, partT, offs, tnode, tne,
                                             sbase, mlist, mcnt);
    place_kernel<<<2048, 256, 0, stream>>>(eattr, eidx, offs, cnt, sea, ssrc);
    lift_kernel<<<2500, 256, 0, stream>>>(x, node_w, node_b, hbf, hmaxb);
    prep_kernel<<<18, 256, 0, stream>>>(edge_w, edge_b, msg_w1, msg_b1, W1p, b1p);
    packall_kernel<<<1024, 256, 0, stream>>>(msg_w1, msg_w2, upd_w1, upd_w2,
                                             mw1f, mw2f, uw1f, uw2f);

    for (int l = 0; l < 2; ++l){
        // Mh = bf16(MLP_msg(h) + b2m) per node  (P-layout out)
        mlp_kernel<0><<<256, 512, SMEM_BYTES, stream>>>(
            hbf, nullptr,
            mw1f + l*32768, msg_b1 + l*256, mw2f + l*32768, msg_b2 + l*128,
            mhb, nullptr, NN/32);
        // zero only aggrH rows needing init (multi-tile or deg==0 nodes)
        mzero_kernel<<<64, 256, 0, stream>>>(mlist, mcnt, aggrH);
        // hidden-space edge aggregation
        edgeh_kernel<<<1024, 512, 0, stream>>>(sea, tnode, tne, sbase,
                                               W1p + l*2048, b1p + l*256, aggrH);
        // aggr_bf = bf16((aggrH @ W2m)*dinv + t*b2m)  (P-layout out)
        p2_kernel<<<256, 512, P2_SMEM, stream>>>(aggrH, mw2f + l*32768,
                                                 msg_b2 + l*128, deg, aggr_bf);
        // aggr_bf += bf16(sum Mh[src] * dinv)
        csr_kernel<<<5000, 512, 0, stream>>>(mhb, ssrc, offs, deg, aggr_bf);
        // h' = MLP_upd(h) + MLP_upd(aggr); hmaxb, hbf update  (P-layout)
        mlp_kernel<1><<<256, 512, SMEM_BYTES, stream>>>(
            hbf, aggr_bf,
            uw1f + l*32768, upd_b1 + l*256, uw2f + l*32768, upd_b2 + l*128,
            hbf, hmaxb, NN/16);
    }

    final_kernel<<<625, 256, 0, stream>>>(hmaxb, fw, fb, out);
}